// Round 4
// baseline (70.047 us; speedup 1.0000x reference)
//
#include <hip/hip_runtime.h>

#define BB 16
#define QQ 64
#define KK 512
#define DD 256
#define HH 256

#define LOG2E2 2.88539008177792681f   // 2*log2(e): exp2(LOG2E2*x) = e^{2x}

__device__ __forceinline__ float fast_exp2(float x) {
#if __has_builtin(__builtin_amdgcn_exp2f)
    return __builtin_amdgcn_exp2f(x);
#else
    return exp2f(x);
#endif
}

// ---------------------------------------------------------------------------
// Both projections in one launch. Y = (X @ W) * 2log2e.
// Key tiles entirely beyond valid_len are skipped (outputs never consumed).
// ---------------------------------------------------------------------------
__global__ __launch_bounds__(256) void proj_both(
        const float* __restrict__ Xq, const float* __restrict__ Wq, float* __restrict__ Yq,
        const float* __restrict__ Xk, const float* __restrict__ Wk, float* __restrict__ Yk,
        const int* __restrict__ valid_lens) {
    __shared__ float XsT[32][68];
    __shared__ float Ws[32][64];
    const int rt = blockIdx.x;
    const float* X; const float* W; float* Y; int row0;
    if (rt < 16) { X = Xq; W = Wq; Y = Yq; row0 = rt * 64; }
    else {
        X = Xk; W = Wk; Y = Yk; row0 = (rt - 16) * 64;
        const int bb    = row0 >> 9;        // 512 key rows per batch
        const int local = row0 & 511;
        if (local >= valid_lens[bb]) return;   // whole tile masked -> dead output
    }
    const int col0 = blockIdx.y * 64;
    const int tid = threadIdx.x;
    const int tx = tid & 15, ty = tid >> 4;

    float acc[4][4] = {};

    for (int k0 = 0; k0 < HH; k0 += 32) {
        {
            const int m  = tid >> 3;
            const int kk = (tid & 7) * 4;
            #pragma unroll
            for (int s = 0; s < 2; ++s) {
                float4 x4 = *(const float4*)(X + (size_t)(row0 + m + 32*s) * HH + k0 + kk);
                XsT[kk+0][m+32*s] = x4.x;
                XsT[kk+1][m+32*s] = x4.y;
                XsT[kk+2][m+32*s] = x4.z;
                XsT[kk+3][m+32*s] = x4.w;
            }
        }
        {
            const int kk = tid >> 4;
            const int c  = (tid & 15) * 4;
            #pragma unroll
            for (int s = 0; s < 2; ++s) {
                float4 w4 = *(const float4*)(W + (size_t)(k0 + kk + 16*s) * HH + col0 + c);
                *(float4*)(&Ws[kk+16*s][c]) = w4;
            }
        }
        __syncthreads();
        #pragma unroll
        for (int kk = 0; kk < 32; ++kk) {
            float4 a = *(const float4*)(&XsT[kk][ty*4]);
            float4 b = *(const float4*)(&Ws[kk][tx*4]);
            acc[0][0] += a.x*b.x; acc[0][1] += a.x*b.y; acc[0][2] += a.x*b.z; acc[0][3] += a.x*b.w;
            acc[1][0] += a.y*b.x; acc[1][1] += a.y*b.y; acc[1][2] += a.y*b.z; acc[1][3] += a.y*b.w;
            acc[2][0] += a.z*b.x; acc[2][1] += a.z*b.y; acc[2][2] += a.z*b.z; acc[2][3] += a.z*b.w;
            acc[3][0] += a.w*b.x; acc[3][1] += a.w*b.y; acc[3][2] += a.w*b.z; acc[3][3] += a.w*b.w;
        }
        __syncthreads();
    }
    #pragma unroll
    for (int i = 0; i < 4; ++i) {
        float4 o = make_float4(acc[i][0]*LOG2E2, acc[i][1]*LOG2E2,
                               acc[i][2]*LOG2E2, acc[i][3]*LOG2E2);
        *(float4*)(Y + (size_t)(row0 + ty*4 + i) * HH + col0 + tx*4) = o;
    }
}

// ---------------------------------------------------------------------------
// Fused scores + masked softmax + PV.
// grid (B, Q/2), block 512 (8 waves). Wave w owns key strip [w*64, w*64+64)
// (vl-clipped, prefetched; 2 q rows share each k load). Scores -> LDS
// (pre-init -1e6 = masked). Then block softmax, then 8-wave k-split PV.
// ---------------------------------------------------------------------------
__device__ __forceinline__ float score_partial(const float4 qv[4], const float4 kv[4],
                                               const float4 nw[4], float wvsum) {
    float a0 = wvsum, a1 = 0.f, a2 = 0.f, a3 = 0.f;
    #pragma unroll
    for (int i = 0; i < 4; ++i) {
        float e0 = fast_exp2(qv[i].x + kv[i].x);
        float e1 = fast_exp2(qv[i].y + kv[i].y);
        float e2 = fast_exp2(qv[i].z + kv[i].z);
        float e3 = fast_exp2(qv[i].w + kv[i].w);
        a0 = fmaf(nw[i].x, __builtin_amdgcn_rcpf(e0 + 1.f), a0);
        a1 = fmaf(nw[i].y, __builtin_amdgcn_rcpf(e1 + 1.f), a1);
        a2 = fmaf(nw[i].z, __builtin_amdgcn_rcpf(e2 + 1.f), a2);
        a3 = fmaf(nw[i].w, __builtin_amdgcn_rcpf(e3 + 1.f), a3);
    }
    return (a0 + a1) + (a2 + a3);
}

__global__ __launch_bounds__(512) void fused_attn(
        const float* __restrict__ qf, const float* __restrict__ kf,
        const float* __restrict__ w_v, const int* __restrict__ valid_lens,
        const float* __restrict__ values, float* __restrict__ out) {
    __shared__ float sc[2][KK];      // 4 KB scores -> probs
    __shared__ float red[8][DD];     // 8 KB PV partials
    __shared__ float wred[16];
    const int b    = blockIdx.x;
    const int q0   = blockIdx.y * 2;
    const int tid  = threadIdx.x;
    const int lane = tid & 63;
    const int w    = tid >> 6;       // 0..7
    const int hg   = lane & 15;
    const int ksub = lane >> 4;
    const int h0   = hg * 16;
    const int vl   = valid_lens[b];

    sc[0][tid] = -1e6f;
    sc[1][tid] = -1e6f;

    float4 nw[4];
    float wvsum = 0.f;
    #pragma unroll
    for (int i = 0; i < 4; ++i) {
        float4 wv = *(const float4*)(w_v + h0 + i*4);
        wvsum += ((wv.x + wv.y) + (wv.z + wv.w));
        nw[i] = make_float4(-2.f*wv.x, -2.f*wv.y, -2.f*wv.z, -2.f*wv.w);
    }
    float4 qA[4], qB[4];
    {
        const float* qrA = qf + (size_t)(b*QQ + q0) * HH + h0;
        const float* qrB = qrA + HH;
        #pragma unroll
        for (int i = 0; i < 4; ++i) {
            qA[i] = *(const float4*)(qrA + i*4);
            qB[i] = *(const float4*)(qrB + i*4);
        }
    }
    __syncthreads();   // sc init visible

    // ---- Phase A: scores for key strip [base, base+64) ----
    {
        const int base = w * 64;
        int cnt = vl - base;
        const int ng = (cnt <= 0) ? 0 : ((cnt >= 64) ? 16 : ((cnt + 3) >> 2));
        const float* kptr = kf + (size_t)(b*KK + base + ksub) * HH + h0;

        float4 kcur[4];
        if (ng > 0) {
            #pragma unroll
            for (int i = 0; i < 4; ++i) kcur[i] = *(const float4*)(kptr + i*4);
        }
        for (int g = 0; g < ng; ++g) {
            float4 knxt[4];
            const bool more = (g + 1 < ng);
            if (more) {
                const float* kp = kptr + (size_t)(g+1) * 4 * HH;
                #pragma unroll
                for (int i = 0; i < 4; ++i) knxt[i] = *(const float4*)(kp + i*4);
            }
            float sA = score_partial(qA, kcur, nw, wvsum);
            float sB = score_partial(qB, kcur, nw, wvsum);
            #pragma unroll
            for (int off = 8; off; off >>= 1) {
                sA += __shfl_xor(sA, off);
                sB += __shfl_xor(sB, off);
            }
            const int k = base + g*4 + ksub;
            if (hg == 0 && k < vl) { sc[0][k] = sA; sc[1][k] = sB; }
            if (more) {
                #pragma unroll
                for (int i = 0; i < 4; ++i) kcur[i] = knxt[i];
            }
        }
    }
    __syncthreads();

    // ---- Phase B: masked softmax (wave w: q = w>>2, chunk = w&3) ----
    {
        const int qq = w >> 2, part = w & 3;
        float2 sv = *(const float2*)(&sc[qq][part*128 + lane*2]);
        float m = fmaxf(sv.x, sv.y);
        #pragma unroll
        for (int off = 32; off; off >>= 1) m = fmaxf(m, __shfl_xor(m, off));
        if (lane == 0) wred[w] = m;
        __syncthreads();
        m = fmaxf(fmaxf(wred[qq*4+0], wred[qq*4+1]), fmaxf(wred[qq*4+2], wred[qq*4+3]));

        float e0 = __expf(sv.x - m), e1 = __expf(sv.y - m);
        float sum = e0 + e1;
        #pragma unroll
        for (int off = 32; off; off >>= 1) sum += __shfl_xor(sum, off);
        if (lane == 0) wred[8 + w] = sum;
        __syncthreads();
        const float tot = (wred[8+qq*4+0] + wred[8+qq*4+1]) + (wred[8+qq*4+2] + wred[8+qq*4+3]);
        const float inv = 1.f / tot;
        *(float2*)(&sc[qq][part*128 + lane*2]) = make_float2(e0*inv, e1*inv);
    }
    __syncthreads();

    // ---- Phase C: PV (wave w: q = w>>2, k chunk = (w&3)*128, vl-clipped) ----
    {
        const int qq = w >> 2;
        const int k0 = (w & 3) * 128;
        int kcnt = vl - k0;
        kcnt = (kcnt < 0) ? 0 : ((kcnt > 128) ? 128 : kcnt);
        float4 acc = make_float4(0.f, 0.f, 0.f, 0.f);
        const float* V = values + ((size_t)b*KK + k0) * DD + lane*4;
        #pragma unroll 4
        for (int k = 0; k < kcnt; ++k) {
            const float pw = sc[qq][k0 + k];
            float4 v4 = *(const float4*)(V + (size_t)k * DD);
            acc.x += pw * v4.x; acc.y += pw * v4.y;
            acc.z += pw * v4.z; acc.w += pw * v4.w;
        }
        *(float4*)(&red[w][lane*4]) = acc;
    }
    __syncthreads();

    {
        const int qq = tid >> 8, d = tid & 255;
        const float o = (red[qq*4+0][d] + red[qq*4+1][d]) + (red[qq*4+2][d] + red[qq*4+3][d]);
        out[(size_t)(b*QQ + q0 + qq) * DD + d] = o;
    }
}

extern "C" void kernel_launch(void* const* d_in, const int* in_sizes, int n_in,
                              void* d_out, int out_size, void* d_ws, size_t ws_size,
                              hipStream_t stream) {
    (void)in_sizes; (void)n_in; (void)out_size; (void)ws_size;
    const float* querys     = (const float*)d_in[0];
    const float* keys       = (const float*)d_in[1];
    const float* values     = (const float*)d_in[2];
    const int*   valid_lens = (const int*)d_in[3];
    const float* Wq         = (const float*)d_in[4];
    const float* Wk         = (const float*)d_in[5];
    const float* w_v        = (const float*)d_in[6];
    float* out = (float*)d_out;

    float* qf    = (float*)d_ws;                      // 1 MB (pre-scaled by 2log2e)
    float* kfeat = qf + (size_t)BB*QQ*HH;             // 8 MB (pre-scaled by 2log2e)

    proj_both<<<dim3(16 + BB*KK/64, HH/64), 256, 0, stream>>>(
        querys, Wq, qf, keys, Wk, kfeat, valid_lens);
    fused_attn<<<dim3(BB, QQ/2), 512, 0, stream>>>(
        qf, kfeat, w_v, valid_lens, values, out);
}